// Round 6
// baseline (403.629 us; speedup 1.0000x reference)
//
#include <hip/hip_runtime.h>
#include <math.h>

// DSoftKI: B=16384, M=512, D=8
//   diff = x[:,None,:]/T - z            [B,M,D]
//   dist = ||diff||                     [B,M]
//   W    = softmax(-dist, axis=-1)      [B,M]
//   dd   = diff/(dist+1e-6)/T           [B,M,D]
//   mean = einsum('bm,bmd->bd', W, dd)  [B,D]
//   deriv= -W*(dd - mean)               [B,M,D]
//   out  = concat([W, deriv.transpose(0,2,1).reshape(B*D, M)])  [B*(D+1), M]
//
// R6: occupancy fix. R2/R4/R5 all ~56-64us vs 44us floor; store pattern and
// block churn falsified. dd[2][4][8] (~130 VGPR) limited us to ONE 512-thr
// block/CU (2 waves/SIMD) -> store bursts (18 instrs) separated by ~1100-cyc
// compute phases leave the store pipe idle. Fix: don't keep dd. Pass 1
// accumulates acc[d] += e*dd on the fly (keeps only e,inv: 16 regs); pass 2
// recomputes dd per c-half from LDS (32 regs live). Target <=85 VGPR via
// __launch_bounds__(512,6) -> 3 blocks/CU, 24 waves/CU: always some wave
// storing. Extra LDS reads/VALU have >=2x slack vs the write floor.

#define B_N 16384
#define M_N 512
#define D_N 8
#define ROWF 20  // floats per LDS row: 8 z + 8 invT + 4 pad (80B stride)
#define LOG2E 1.4426950408889634f

typedef float f32x4 __attribute__((ext_vector_type(4)));

__global__ __launch_bounds__(512, 6) void dsoftki_kernel(
    const float* __restrict__ x,
    const float* __restrict__ z,
    const float* __restrict__ T,
    float* __restrict__ out)
{
    __shared__ float zt[M_N * ROWF];  // 40 KB

    const int tid = threadIdx.x;

    // ---- stage z and 1/T into LDS, iterating by slot (once per block) ----
    // slot s (= tid) holds m = c*256 + q*4 + j where j=s>>7, c=(s>>6)&1, q=s&63
    {
        const int s = tid;  // M_N == 512 == blockDim.x
        const int j = s >> 7;
        const int c = (s >> 6) & 1;
        const int q = s & 63;
        const int m = c * 256 + q * 4 + j;
        const float4* zp = (const float4*)(z + m * 8);
        float4 z0 = zp[0], z1 = zp[1];
        const float4* tp = (const float4*)(T + m * 8);
        float4 t0 = tp[0], t1 = tp[1];
        float* row = zt + s * ROWF;
        ((float4*)row)[0] = z0;
        ((float4*)row)[1] = z1;
        row[8]  = __builtin_amdgcn_rcpf(t0.x);
        row[9]  = __builtin_amdgcn_rcpf(t0.y);
        row[10] = __builtin_amdgcn_rcpf(t0.z);
        row[11] = __builtin_amdgcn_rcpf(t0.w);
        row[12] = __builtin_amdgcn_rcpf(t1.x);
        row[13] = __builtin_amdgcn_rcpf(t1.y);
        row[14] = __builtin_amdgcn_rcpf(t1.z);
        row[15] = __builtin_amdgcn_rcpf(t1.w);
    }
    __syncthreads();

    const int wave = tid >> 6;
    const int lane = tid & 63;
    const int b = blockIdx.x * 8 + wave;

    // ---- x[b] (broadcast load, L1-served) ----
    float xb[8];
    {
        const float4* xp = (const float4*)(x + (size_t)b * 8);
        float4 x0 = xp[0], x1 = xp[1];
        xb[0] = x0.x; xb[1] = x0.y; xb[2] = x0.z; xb[3] = x0.w;
        xb[4] = x1.x; xb[5] = x1.y; xb[6] = x1.z; xb[7] = x1.w;
    }

    // ---- pass 1: e, inv, and on-the-fly acc[d] = sum e*dd (no dd kept) ----
    // lane owns m = c*256 + lane*4 + j, staged at slot j*128 + c*64 + lane
    float e[2][4];
    float inv_[2][4];
    float acc[8] = {0.f, 0.f, 0.f, 0.f, 0.f, 0.f, 0.f, 0.f};

    #pragma unroll
    for (int c = 0; c < 2; ++c) {
        #pragma unroll
        for (int j = 0; j < 4; ++j) {
            const float* row = zt + (j * 128 + c * 64 + lane) * ROWF;
            float4 zz0 = ((const float4*)row)[0];
            float4 zz1 = ((const float4*)row)[1];
            float4 it0 = ((const float4*)row)[2];
            float4 it1 = ((const float4*)row)[3];
            float zr[8] = {zz0.x, zz0.y, zz0.z, zz0.w, zz1.x, zz1.y, zz1.z, zz1.w};
            float ir[8] = {it0.x, it0.y, it0.z, it0.w, it1.x, it1.y, it1.z, it1.w};

            float df[8];
            float ss = 0.f;
            #pragma unroll
            for (int d = 0; d < 8; ++d) {
                df[d] = xb[d] * ir[d] - zr[d];   // x/T - z
                ss = fmaf(df[d], df[d], ss);
            }
            float dist = __builtin_amdgcn_sqrtf(ss);
            // exp(-dist), dist in [0,~25]: no overflow/underflow; max-sub skipped.
            float ee = __builtin_amdgcn_exp2f(-dist * LOG2E);
            float iv = __builtin_amdgcn_rcpf(dist + 1e-6f);
            e[c][j] = ee;
            inv_[c][j] = iv;
            float s = ee * iv;
            #pragma unroll
            for (int d = 0; d < 8; ++d)
                acc[d] = fmaf(df[d] * ir[d], s, acc[d]);   // += e * dd
        }
    }

    // ---- 9 independent wave reductions: se = sum e, acc[d] reduce ----
    float se = 0.f;
    #pragma unroll
    for (int c = 0; c < 2; ++c)
        #pragma unroll
        for (int j = 0; j < 4; ++j) se += e[c][j];

    #pragma unroll
    for (int o = 32; o > 0; o >>= 1) {
        se += __shfl_xor(se, o, 64);
        #pragma unroll
        for (int d = 0; d < 8; ++d) acc[d] += __shfl_xor(acc[d], o, 64);
    }
    const float sinv = __builtin_amdgcn_rcpf(se);

    // ---- W stores (contiguous 1KB per instruction) ----
    float w[2][4];
    #pragma unroll
    for (int c = 0; c < 2; ++c)
        #pragma unroll
        for (int j = 0; j < 4; ++j) w[c][j] = e[c][j] * sinv;
    {
        float* p = out + (size_t)b * M_N;
        #pragma unroll
        for (int c = 0; c < 2; ++c) {
            f32x4 wv = {w[c][0], w[c][1], w[c][2], w[c][3]};
            __builtin_nontemporal_store(wv, (f32x4*)(p + c * 256 + lane * 4));
        }
    }

    float meanv[8];
    #pragma unroll
    for (int d = 0; d < 8; ++d) meanv[d] = acc[d] * sinv;

    // ---- pass 2: recompute dd per c-half (32 regs live), store deriv ----
    float* outD = out + (size_t)B_N * M_N + (size_t)b * (D_N * M_N);
    #pragma unroll
    for (int c = 0; c < 2; ++c) {
        float ddc[4][8];
        #pragma unroll
        for (int j = 0; j < 4; ++j) {
            const float* row = zt + (j * 128 + c * 64 + lane) * ROWF;
            float4 zz0 = ((const float4*)row)[0];
            float4 zz1 = ((const float4*)row)[1];
            float4 it0 = ((const float4*)row)[2];
            float4 it1 = ((const float4*)row)[3];
            float zr[8] = {zz0.x, zz0.y, zz0.z, zz0.w, zz1.x, zz1.y, zz1.z, zz1.w};
            float ir[8] = {it0.x, it0.y, it0.z, it0.w, it1.x, it1.y, it1.z, it1.w};
            float iv = inv_[c][j];
            #pragma unroll
            for (int d = 0; d < 8; ++d) {
                float df = xb[d] * ir[d] - zr[d];
                ddc[j][d] = df * ir[d] * iv;
            }
        }
        #pragma unroll
        for (int d = 0; d < 8; ++d) {
            f32x4 v = {w[c][0] * (meanv[d] - ddc[0][d]),
                       w[c][1] * (meanv[d] - ddc[1][d]),
                       w[c][2] * (meanv[d] - ddc[2][d]),
                       w[c][3] * (meanv[d] - ddc[3][d])};
            __builtin_nontemporal_store(v, (f32x4*)(outD + d * M_N + c * 256 + lane * 4));
        }
    }
}

extern "C" void kernel_launch(void* const* d_in, const int* in_sizes, int n_in,
                              void* d_out, int out_size, void* d_ws, size_t ws_size,
                              hipStream_t stream) {
    const float* x = (const float*)d_in[0];
    const float* z = (const float*)d_in[1];
    const float* T = (const float*)d_in[2];
    float* out = (float*)d_out;

    dim3 grid(B_N / 8);   // 8 waves per block, 1 batch row per wave
    dim3 block(512);
    dsoftki_kernel<<<grid, block, 0, stream>>>(x, z, T, out);
}

// Round 7
// 186.459 us; speedup vs baseline: 2.1647x; 2.1647x over previous
//
#include <hip/hip_runtime.h>
#include <math.h>

// DSoftKI: B=16384, M=512, D=8
//   diff = x[:,None,:]/T - z            [B,M,D]
//   dist = ||diff||                     [B,M]
//   W    = softmax(-dist, axis=-1)      [B,M]
//   dd   = diff/(dist+1e-6)/T           [B,M,D]
//   mean = einsum('bm,bmd->bd', W, dd)  [B,D]
//   deriv= -W*(dd - mean)               [B,M,D]
//   out  = concat([W, deriv.transpose(0,2,1).reshape(B*D, M)])  [B*(D+1), M]
//
// R7: occupancy theory, correct implementation. R6's launch_bounds(512,6)
// forced 40 VGPR -> scratch spill (FETCH 409MB, WRITE 1.14GB, 404us). The
// two-pass structure needs ~96 VGPR; cap at 128 via launch_bounds(512,4):
// no spill, guaranteed 4 waves/SIMD = 16 waves/CU (2 blocks) = 2x R2's
// occupancy. Pass 1: e, inv, on-the-fly acc[d]. Pass 2: recompute dd per
// c-half from LDS, store deriv. Store layout = R4's contiguous 1KB/instr.

#define B_N 16384
#define M_N 512
#define D_N 8
#define ROWF 20  // floats per LDS row: 8 z + 8 invT + 4 pad (80B stride)
#define LOG2E 1.4426950408889634f

typedef float f32x4 __attribute__((ext_vector_type(4)));

__global__ __launch_bounds__(512, 4) void dsoftki_kernel(
    const float* __restrict__ x,
    const float* __restrict__ z,
    const float* __restrict__ T,
    float* __restrict__ out)
{
    __shared__ float zt[M_N * ROWF];  // 40 KB

    const int tid = threadIdx.x;

    // ---- stage z and 1/T into LDS, iterating by slot (once per block) ----
    // slot s (= tid) holds m = c*256 + q*4 + j where j=s>>7, c=(s>>6)&1, q=s&63
    {
        const int s = tid;  // M_N == 512 == blockDim.x
        const int j = s >> 7;
        const int c = (s >> 6) & 1;
        const int q = s & 63;
        const int m = c * 256 + q * 4 + j;
        const float4* zp = (const float4*)(z + m * 8);
        float4 z0 = zp[0], z1 = zp[1];
        const float4* tp = (const float4*)(T + m * 8);
        float4 t0 = tp[0], t1 = tp[1];
        float* row = zt + s * ROWF;
        ((float4*)row)[0] = z0;
        ((float4*)row)[1] = z1;
        row[8]  = __builtin_amdgcn_rcpf(t0.x);
        row[9]  = __builtin_amdgcn_rcpf(t0.y);
        row[10] = __builtin_amdgcn_rcpf(t0.z);
        row[11] = __builtin_amdgcn_rcpf(t0.w);
        row[12] = __builtin_amdgcn_rcpf(t1.x);
        row[13] = __builtin_amdgcn_rcpf(t1.y);
        row[14] = __builtin_amdgcn_rcpf(t1.z);
        row[15] = __builtin_amdgcn_rcpf(t1.w);
    }
    __syncthreads();

    const int wave = tid >> 6;
    const int lane = tid & 63;
    const int b = blockIdx.x * 8 + wave;

    // ---- x[b] (broadcast load, L1-served) ----
    float xb[8];
    {
        const float4* xp = (const float4*)(x + (size_t)b * 8);
        float4 x0 = xp[0], x1 = xp[1];
        xb[0] = x0.x; xb[1] = x0.y; xb[2] = x0.z; xb[3] = x0.w;
        xb[4] = x1.x; xb[5] = x1.y; xb[6] = x1.z; xb[7] = x1.w;
    }

    // ---- pass 1: e, inv, and on-the-fly acc[d] = sum e*dd (no dd kept) ----
    // lane owns m = c*256 + lane*4 + j, staged at slot j*128 + c*64 + lane
    float e[2][4];
    float inv_[2][4];
    float acc[8] = {0.f, 0.f, 0.f, 0.f, 0.f, 0.f, 0.f, 0.f};

    #pragma unroll
    for (int c = 0; c < 2; ++c) {
        #pragma unroll
        for (int j = 0; j < 4; ++j) {
            const float* row = zt + (j * 128 + c * 64 + lane) * ROWF;
            float4 zz0 = ((const float4*)row)[0];
            float4 zz1 = ((const float4*)row)[1];
            float4 it0 = ((const float4*)row)[2];
            float4 it1 = ((const float4*)row)[3];
            float zr[8] = {zz0.x, zz0.y, zz0.z, zz0.w, zz1.x, zz1.y, zz1.z, zz1.w};
            float ir[8] = {it0.x, it0.y, it0.z, it0.w, it1.x, it1.y, it1.z, it1.w};

            float df[8];
            float ss = 0.f;
            #pragma unroll
            for (int d = 0; d < 8; ++d) {
                df[d] = xb[d] * ir[d] - zr[d];   // x/T - z
                ss = fmaf(df[d], df[d], ss);
            }
            float dist = __builtin_amdgcn_sqrtf(ss);
            // exp(-dist), dist in [0,~25]: no overflow/underflow; max-sub skipped.
            float ee = __builtin_amdgcn_exp2f(-dist * LOG2E);
            float iv = __builtin_amdgcn_rcpf(dist + 1e-6f);
            e[c][j] = ee;
            inv_[c][j] = iv;
            float s = ee * iv;
            #pragma unroll
            for (int d = 0; d < 8; ++d)
                acc[d] = fmaf(df[d] * ir[d], s, acc[d]);   // += e * dd
        }
    }

    // ---- 9 independent wave reductions: se = sum e, acc[d] reduce ----
    float se = 0.f;
    #pragma unroll
    for (int c = 0; c < 2; ++c)
        #pragma unroll
        for (int j = 0; j < 4; ++j) se += e[c][j];

    #pragma unroll
    for (int o = 32; o > 0; o >>= 1) {
        se += __shfl_xor(se, o, 64);
        #pragma unroll
        for (int d = 0; d < 8; ++d) acc[d] += __shfl_xor(acc[d], o, 64);
    }
    const float sinv = __builtin_amdgcn_rcpf(se);

    // ---- W stores (contiguous 1KB per instruction) ----
    float w[2][4];
    #pragma unroll
    for (int c = 0; c < 2; ++c)
        #pragma unroll
        for (int j = 0; j < 4; ++j) w[c][j] = e[c][j] * sinv;
    {
        float* p = out + (size_t)b * M_N;
        #pragma unroll
        for (int c = 0; c < 2; ++c) {
            f32x4 wv = {w[c][0], w[c][1], w[c][2], w[c][3]};
            __builtin_nontemporal_store(wv, (f32x4*)(p + c * 256 + lane * 4));
        }
    }

    float meanv[8];
    #pragma unroll
    for (int d = 0; d < 8; ++d) meanv[d] = acc[d] * sinv;

    // ---- pass 2: recompute dd per c-half (32 regs live), store deriv ----
    float* outD = out + (size_t)B_N * M_N + (size_t)b * (D_N * M_N);
    #pragma unroll
    for (int c = 0; c < 2; ++c) {
        float ddc[4][8];
        #pragma unroll
        for (int j = 0; j < 4; ++j) {
            const float* row = zt + (j * 128 + c * 64 + lane) * ROWF;
            float4 zz0 = ((const float4*)row)[0];
            float4 zz1 = ((const float4*)row)[1];
            float4 it0 = ((const float4*)row)[2];
            float4 it1 = ((const float4*)row)[3];
            float zr[8] = {zz0.x, zz0.y, zz0.z, zz0.w, zz1.x, zz1.y, zz1.z, zz1.w};
            float ir[8] = {it0.x, it0.y, it0.z, it0.w, it1.x, it1.y, it1.z, it1.w};
            float iv = inv_[c][j];
            #pragma unroll
            for (int d = 0; d < 8; ++d) {
                float df = xb[d] * ir[d] - zr[d];
                ddc[j][d] = df * ir[d] * iv;
            }
        }
        #pragma unroll
        for (int d = 0; d < 8; ++d) {
            f32x4 v = {w[c][0] * (meanv[d] - ddc[0][d]),
                       w[c][1] * (meanv[d] - ddc[1][d]),
                       w[c][2] * (meanv[d] - ddc[2][d]),
                       w[c][3] * (meanv[d] - ddc[3][d])};
            __builtin_nontemporal_store(v, (f32x4*)(outD + d * M_N + c * 256 + lane * 4));
        }
    }
}

extern "C" void kernel_launch(void* const* d_in, const int* in_sizes, int n_in,
                              void* d_out, int out_size, void* d_ws, size_t ws_size,
                              hipStream_t stream) {
    const float* x = (const float*)d_in[0];
    const float* z = (const float*)d_in[1];
    const float* T = (const float*)d_in[2];
    float* out = (float*)d_out;

    dim3 grid(B_N / 8);   // 8 waves per block, 1 batch row per wave
    dim3 block(512);
    dsoftki_kernel<<<grid, block, 0, stream>>>(x, z, T, out);
}

// Round 8
// 96.121 us; speedup vs baseline: 4.1992x; 1.9398x over previous
//
#include <hip/hip_runtime.h>
#include <math.h>

// DSoftKI: B=16384, M=512, D=8
//   diff = x[:,None,:]/T - z            [B,M,D]
//   dist = ||diff||                     [B,M]
//   W    = softmax(-dist, axis=-1)      [B,M]
//   dd   = diff/(dist+1e-6)/T           [B,M,D]
//   mean = einsum('bm,bmd->bd', W, dd)  [B,D]
//   deriv= -W*(dd - mean)               [B,M,D]
//   out  = concat([W, deriv.transpose(0,2,1).reshape(B*D, M)])  [B*(D+1), M]
//
// R8: occupancy theory, third attempt. Empirical launch_bounds semantics on
// this compiler (512-thr blocks): VGPR cap = 2048/(8*arg). arg=6 -> 40 VGPR
// (spill, 404us), arg=4 -> 64 VGPR (spill, 186us). arg=2 -> cap 128, fits
// the ~100-reg two-pass structure with NO spill, guarantees 2 blocks/CU =
// 16 waves/CU (2x R2). Pass 1: e, inv, on-the-fly acc[d]. Pass 2: recompute
// dd per c-half from LDS. Store layout: contiguous 1KB/instr dwordx4 nt.

#define B_N 16384
#define M_N 512
#define D_N 8
#define ROWF 20  // floats per LDS row: 8 z + 8 invT + 4 pad (80B stride)
#define LOG2E 1.4426950408889634f

typedef float f32x4 __attribute__((ext_vector_type(4)));

__global__ __launch_bounds__(512, 2) void dsoftki_kernel(
    const float* __restrict__ x,
    const float* __restrict__ z,
    const float* __restrict__ T,
    float* __restrict__ out)
{
    __shared__ float zt[M_N * ROWF];  // 40 KB

    const int tid = threadIdx.x;

    // ---- stage z and 1/T into LDS, iterating by slot (once per block) ----
    // slot s (= tid) holds m = c*256 + q*4 + j where j=s>>7, c=(s>>6)&1, q=s&63
    {
        const int s = tid;  // M_N == 512 == blockDim.x
        const int j = s >> 7;
        const int c = (s >> 6) & 1;
        const int q = s & 63;
        const int m = c * 256 + q * 4 + j;
        const float4* zp = (const float4*)(z + m * 8);
        float4 z0 = zp[0], z1 = zp[1];
        const float4* tp = (const float4*)(T + m * 8);
        float4 t0 = tp[0], t1 = tp[1];
        float* row = zt + s * ROWF;
        ((float4*)row)[0] = z0;
        ((float4*)row)[1] = z1;
        row[8]  = __builtin_amdgcn_rcpf(t0.x);
        row[9]  = __builtin_amdgcn_rcpf(t0.y);
        row[10] = __builtin_amdgcn_rcpf(t0.z);
        row[11] = __builtin_amdgcn_rcpf(t0.w);
        row[12] = __builtin_amdgcn_rcpf(t1.x);
        row[13] = __builtin_amdgcn_rcpf(t1.y);
        row[14] = __builtin_amdgcn_rcpf(t1.z);
        row[15] = __builtin_amdgcn_rcpf(t1.w);
    }
    __syncthreads();

    const int wave = tid >> 6;
    const int lane = tid & 63;
    const int b = blockIdx.x * 8 + wave;

    // ---- x[b] (broadcast load, L1-served) ----
    float xb[8];
    {
        const float4* xp = (const float4*)(x + (size_t)b * 8);
        float4 x0 = xp[0], x1 = xp[1];
        xb[0] = x0.x; xb[1] = x0.y; xb[2] = x0.z; xb[3] = x0.w;
        xb[4] = x1.x; xb[5] = x1.y; xb[6] = x1.z; xb[7] = x1.w;
    }

    // ---- pass 1: e, inv, and on-the-fly acc[d] = sum e*dd (no dd kept) ----
    // lane owns m = c*256 + lane*4 + j, staged at slot j*128 + c*64 + lane
    float e[2][4];
    float inv_[2][4];
    float acc[8] = {0.f, 0.f, 0.f, 0.f, 0.f, 0.f, 0.f, 0.f};

    #pragma unroll
    for (int c = 0; c < 2; ++c) {
        #pragma unroll
        for (int j = 0; j < 4; ++j) {
            const float* row = zt + (j * 128 + c * 64 + lane) * ROWF;
            float4 zz0 = ((const float4*)row)[0];
            float4 zz1 = ((const float4*)row)[1];
            float4 it0 = ((const float4*)row)[2];
            float4 it1 = ((const float4*)row)[3];
            float zr[8] = {zz0.x, zz0.y, zz0.z, zz0.w, zz1.x, zz1.y, zz1.z, zz1.w};
            float ir[8] = {it0.x, it0.y, it0.z, it0.w, it1.x, it1.y, it1.z, it1.w};

            float df[8];
            float ss = 0.f;
            #pragma unroll
            for (int d = 0; d < 8; ++d) {
                df[d] = xb[d] * ir[d] - zr[d];   // x/T - z
                ss = fmaf(df[d], df[d], ss);
            }
            float dist = __builtin_amdgcn_sqrtf(ss);
            // exp(-dist), dist in [0,~25]: no overflow/underflow; max-sub skipped.
            float ee = __builtin_amdgcn_exp2f(-dist * LOG2E);
            float iv = __builtin_amdgcn_rcpf(dist + 1e-6f);
            e[c][j] = ee;
            inv_[c][j] = iv;
            float s = ee * iv;
            #pragma unroll
            for (int d = 0; d < 8; ++d)
                acc[d] = fmaf(df[d] * ir[d], s, acc[d]);   // += e * dd
        }
    }

    // ---- 9 independent wave reductions: se = sum e, acc[d] reduce ----
    float se = 0.f;
    #pragma unroll
    for (int c = 0; c < 2; ++c)
        #pragma unroll
        for (int j = 0; j < 4; ++j) se += e[c][j];

    #pragma unroll
    for (int o = 32; o > 0; o >>= 1) {
        se += __shfl_xor(se, o, 64);
        #pragma unroll
        for (int d = 0; d < 8; ++d) acc[d] += __shfl_xor(acc[d], o, 64);
    }
    const float sinv = __builtin_amdgcn_rcpf(se);

    // ---- W stores (contiguous 1KB per instruction) ----
    float w[2][4];
    #pragma unroll
    for (int c = 0; c < 2; ++c)
        #pragma unroll
        for (int j = 0; j < 4; ++j) w[c][j] = e[c][j] * sinv;
    {
        float* p = out + (size_t)b * M_N;
        #pragma unroll
        for (int c = 0; c < 2; ++c) {
            f32x4 wv = {w[c][0], w[c][1], w[c][2], w[c][3]};
            __builtin_nontemporal_store(wv, (f32x4*)(p + c * 256 + lane * 4));
        }
    }

    float meanv[8];
    #pragma unroll
    for (int d = 0; d < 8; ++d) meanv[d] = acc[d] * sinv;

    // ---- pass 2: recompute dd per c-half (32 regs live), store deriv ----
    float* outD = out + (size_t)B_N * M_N + (size_t)b * (D_N * M_N);
    #pragma unroll
    for (int c = 0; c < 2; ++c) {
        float ddc[4][8];
        #pragma unroll
        for (int j = 0; j < 4; ++j) {
            const float* row = zt + (j * 128 + c * 64 + lane) * ROWF;
            float4 zz0 = ((const float4*)row)[0];
            float4 zz1 = ((const float4*)row)[1];
            float4 it0 = ((const float4*)row)[2];
            float4 it1 = ((const float4*)row)[3];
            float zr[8] = {zz0.x, zz0.y, zz0.z, zz0.w, zz1.x, zz1.y, zz1.z, zz1.w};
            float ir[8] = {it0.x, it0.y, it0.z, it0.w, it1.x, it1.y, it1.z, it1.w};
            float iv = inv_[c][j];
            #pragma unroll
            for (int d = 0; d < 8; ++d) {
                float df = xb[d] * ir[d] - zr[d];
                ddc[j][d] = df * ir[d] * iv;
            }
        }
        #pragma unroll
        for (int d = 0; d < 8; ++d) {
            f32x4 v = {w[c][0] * (meanv[d] - ddc[0][d]),
                       w[c][1] * (meanv[d] - ddc[1][d]),
                       w[c][2] * (meanv[d] - ddc[2][d]),
                       w[c][3] * (meanv[d] - ddc[3][d])};
            __builtin_nontemporal_store(v, (f32x4*)(outD + d * M_N + c * 256 + lane * 4));
        }
    }
}

extern "C" void kernel_launch(void* const* d_in, const int* in_sizes, int n_in,
                              void* d_out, int out_size, void* d_ws, size_t ws_size,
                              hipStream_t stream) {
    const float* x = (const float*)d_in[0];
    const float* z = (const float*)d_in[1];
    const float* T = (const float*)d_in[2];
    float* out = (float*)d_out;

    dim3 grid(B_N / 8);   // 8 waves per block, 1 batch row per wave
    dim3 block(512);
    dsoftki_kernel<<<grid, block, 0, stream>>>(x, z, T, out);
}

// Round 9
// 59.495 us; speedup vs baseline: 6.7842x; 1.6156x over previous
//
#include <hip/hip_runtime.h>
#include <math.h>

// DSoftKI: B=16384, M=512, D=8
//   diff = x[:,None,:]/T - z            [B,M,D]
//   dist = ||diff||                     [B,M]
//   W    = softmax(-dist, axis=-1)      [B,M]
//   dd   = diff/(dist+1e-6)/T           [B,M,D]
//   mean = einsum('bm,bmd->bd', W, dd)  [B,D]
//   deriv= -W*(dd - mean)               [B,M,D]
//   out  = concat([W, deriv.transpose(0,2,1).reshape(B*D, M)])  [B*(D+1), M]
//
// R9: nt-store ablation on the best kernel (R2, 56.2us). Falsified so far:
// store width (R3/R4), block churn (R5), occupancy (R6-R8, incl. the
// empirical launch_bounds lesson: 2nd arg acts as blocks/CU here, VGPR cap
// = 2048/(8*arg) for 512-thr blocks). Realistic mixed ceiling = 330 MB @
// 6.3-6.9 TB/s = 48-52us; R2 is 8-17% over. Last lever: nontemporal hint
// bypasses L2, throttling each wave's store burst on the HBM write queue;
// plain stores land in L2 (32 MB buffer) and evict asynchronously. Exact
// R2 code, nt -> plain stores, nothing else.

#define B_N 16384
#define M_N 512
#define D_N 8
#define ROWF 20  // floats per LDS row: 8 z + 8 invT + 4 pad (80B stride)
#define LOG2E 1.4426950408889634f

__global__ __launch_bounds__(512) void dsoftki_kernel(
    const float* __restrict__ x,
    const float* __restrict__ z,
    const float* __restrict__ T,
    float* __restrict__ out)
{
    __shared__ float zt[M_N * ROWF];  // 40 KB

    const int tid = threadIdx.x;

    // ---- stage z and 1/T into LDS (once per block; 512 threads = 512 rows) ----
    {
        const int m = tid;  // M_N == 512 == blockDim.x
        const float4* zp = (const float4*)(z + m * 8);
        float4 z0 = zp[0], z1 = zp[1];
        const float4* tp = (const float4*)(T + m * 8);
        float4 t0 = tp[0], t1 = tp[1];
        float* row = zt + m * ROWF;
        ((float4*)row)[0] = z0;
        ((float4*)row)[1] = z1;
        row[8]  = __builtin_amdgcn_rcpf(t0.x);
        row[9]  = __builtin_amdgcn_rcpf(t0.y);
        row[10] = __builtin_amdgcn_rcpf(t0.z);
        row[11] = __builtin_amdgcn_rcpf(t0.w);
        row[12] = __builtin_amdgcn_rcpf(t1.x);
        row[13] = __builtin_amdgcn_rcpf(t1.y);
        row[14] = __builtin_amdgcn_rcpf(t1.z);
        row[15] = __builtin_amdgcn_rcpf(t1.w);
    }
    __syncthreads();

    const int wave = tid >> 6;
    const int lane = tid & 63;
    const int b = blockIdx.x * 8 + wave;

    // ---- x[b] (broadcast load, L1-served) ----
    float xb[8];
    {
        const float4* xp = (const float4*)(x + (size_t)b * 8);
        float4 x0 = xp[0], x1 = xp[1];
        xb[0] = x0.x; xb[1] = x0.y; xb[2] = x0.z; xb[3] = x0.w;
        xb[4] = x1.x; xb[5] = x1.y; xb[6] = x1.z; xb[7] = x1.w;
    }

    // ---- pass: dist + dd (kept in regs), unnormalized weights e[k] ----
    float dd[8][8];
    float e[8];

    #pragma unroll
    for (int k = 0; k < 8; ++k) {
        const float* row = zt + ((k << 6) + lane) * ROWF;
        float4 zz0 = ((const float4*)row)[0];
        float4 zz1 = ((const float4*)row)[1];
        float4 it0 = ((const float4*)row)[2];
        float4 it1 = ((const float4*)row)[3];
        float zr[8] = {zz0.x, zz0.y, zz0.z, zz0.w, zz1.x, zz1.y, zz1.z, zz1.w};
        float ir[8] = {it0.x, it0.y, it0.z, it0.w, it1.x, it1.y, it1.z, it1.w};

        float diff[8];
        float ss = 0.f;
        #pragma unroll
        for (int d = 0; d < 8; ++d) {
            float df = xb[d] * ir[d] - zr[d];   // x/T - z
            diff[d] = df * ir[d];               // pre-scale by 1/T for dd
            ss = fmaf(df, df, ss);
        }
        float dist = __builtin_amdgcn_sqrtf(ss);
        // exp(-dist), dist in [0, ~25]: no overflow/underflow; max-sub skipped.
        e[k] = __builtin_amdgcn_exp2f(-dist * LOG2E);
        float inv = __builtin_amdgcn_rcpf(dist + 1e-6f);
        #pragma unroll
        for (int d = 0; d < 8; ++d) dd[k][d] = diff[d] * inv;
    }

    // ---- 9 independent wave reductions: se = sum e, acc[d] = sum e*dd ----
    float se = e[0] + e[1] + e[2] + e[3] + e[4] + e[5] + e[6] + e[7];
    float acc[8];
    #pragma unroll
    for (int d = 0; d < 8; ++d) {
        float a = 0.f;
        #pragma unroll
        for (int k = 0; k < 8; ++k) a = fmaf(e[k], dd[k][d], a);
        acc[d] = a;
    }
    #pragma unroll
    for (int o = 32; o > 0; o >>= 1) {
        se += __shfl_xor(se, o, 64);
        #pragma unroll
        for (int d = 0; d < 8; ++d) acc[d] += __shfl_xor(acc[d], o, 64);
    }
    const float sinv = __builtin_amdgcn_rcpf(se);

    // ---- W stores first (start HBM early); PLAIN stores (through L2) ----
    float w[8];
    float* outW = out + (size_t)b * M_N;
    #pragma unroll
    for (int k = 0; k < 8; ++k) {
        w[k] = e[k] * sinv;
        outW[k * 64 + lane] = w[k];
    }

    // ---- deriv = w*(mean - dd), mean[d] = acc[d]*sinv ----
    float meanv[8];
    #pragma unroll
    for (int d = 0; d < 8; ++d) meanv[d] = acc[d] * sinv;

    float* outD = out + (size_t)B_N * M_N + (size_t)b * (D_N * M_N);
    #pragma unroll
    for (int d = 0; d < 8; ++d) {
        #pragma unroll
        for (int k = 0; k < 8; ++k) {
            float v = w[k] * (meanv[d] - dd[k][d]);
            outD[d * M_N + k * 64 + lane] = v;
        }
    }
}

extern "C" void kernel_launch(void* const* d_in, const int* in_sizes, int n_in,
                              void* d_out, int out_size, void* d_ws, size_t ws_size,
                              hipStream_t stream) {
    const float* x = (const float*)d_in[0];
    const float* z = (const float*)d_in[1];
    const float* T = (const float*)d_in[2];
    float* out = (float*)d_out;

    dim3 grid(B_N / 8);   // 8 waves per block, 1 batch row per wave
    dim3 block(512);
    dsoftki_kernel<<<grid, block, 0, stream>>>(x, z, T, out);
}

// Round 10
// 56.260 us; speedup vs baseline: 7.1744x; 1.0575x over previous
//
#include <hip/hip_runtime.h>
#include <math.h>

// DSoftKI: B=16384, M=512, D=8
//   diff = x[:,None,:]/T - z            [B,M,D]
//   dist = ||diff||                     [B,M]
//   W    = softmax(-dist, axis=-1)      [B,M]
//   dd   = diff/(dist+1e-6)/T           [B,M,D]
//   mean = einsum('bm,bmd->bd', W, dd)  [B,D]
//   deriv= -W*(dd - mean)               [B,M,D]
//   out  = concat([W, deriv.transpose(0,2,1).reshape(B*D, M)])  [B*(D+1), M]
//
// R10 = R2 reverted (best: 56.2us). Output 302MB + 26MB fetch at ~5.4 TB/s
// effective = ~85% of fill-rate; within ~10% of realistic mixed ceiling.
// Falsified levers: store width/pattern (R3/R4), block churn (R5),
// occupancy (R6-R8; launch_bounds 2nd arg = blocks/CU here, VGPR cap
// 2048/(8*arg) @512thr), recompute-for-occupancy (R8), nt-vs-plain (R9:
// nt helps ~3us). Structure: 1 wave per b, z+1/T staged once in LDS
// (80B-padded rows, conflict-free b128 reads), dd[8][8] in regs, native
// v_exp/v_rcp/v_sqrt (no max-sub: dist>=0 bounds exp in (0,1]), 9
// independent shfl_xor butterflies, scalar coalesced nt stores.

#define B_N 16384
#define M_N 512
#define D_N 8
#define ROWF 20  // floats per LDS row: 8 z + 8 invT + 4 pad (80B stride)
#define LOG2E 1.4426950408889634f

__global__ __launch_bounds__(512) void dsoftki_kernel(
    const float* __restrict__ x,
    const float* __restrict__ z,
    const float* __restrict__ T,
    float* __restrict__ out)
{
    __shared__ float zt[M_N * ROWF];  // 40 KB

    const int tid = threadIdx.x;

    // ---- stage z and 1/T into LDS (once per block; 512 threads = 512 rows) ----
    {
        const int m = tid;  // M_N == 512 == blockDim.x
        const float4* zp = (const float4*)(z + m * 8);
        float4 z0 = zp[0], z1 = zp[1];
        const float4* tp = (const float4*)(T + m * 8);
        float4 t0 = tp[0], t1 = tp[1];
        float* row = zt + m * ROWF;
        ((float4*)row)[0] = z0;
        ((float4*)row)[1] = z1;
        row[8]  = __builtin_amdgcn_rcpf(t0.x);
        row[9]  = __builtin_amdgcn_rcpf(t0.y);
        row[10] = __builtin_amdgcn_rcpf(t0.z);
        row[11] = __builtin_amdgcn_rcpf(t0.w);
        row[12] = __builtin_amdgcn_rcpf(t1.x);
        row[13] = __builtin_amdgcn_rcpf(t1.y);
        row[14] = __builtin_amdgcn_rcpf(t1.z);
        row[15] = __builtin_amdgcn_rcpf(t1.w);
    }
    __syncthreads();

    const int wave = tid >> 6;
    const int lane = tid & 63;
    const int b = blockIdx.x * 8 + wave;

    // ---- x[b] (broadcast load, L1-served) ----
    float xb[8];
    {
        const float4* xp = (const float4*)(x + (size_t)b * 8);
        float4 x0 = xp[0], x1 = xp[1];
        xb[0] = x0.x; xb[1] = x0.y; xb[2] = x0.z; xb[3] = x0.w;
        xb[4] = x1.x; xb[5] = x1.y; xb[6] = x1.z; xb[7] = x1.w;
    }

    // ---- pass: dist + dd (kept in regs), unnormalized weights e[k] ----
    float dd[8][8];
    float e[8];

    #pragma unroll
    for (int k = 0; k < 8; ++k) {
        const float* row = zt + ((k << 6) + lane) * ROWF;
        float4 zz0 = ((const float4*)row)[0];
        float4 zz1 = ((const float4*)row)[1];
        float4 it0 = ((const float4*)row)[2];
        float4 it1 = ((const float4*)row)[3];
        float zr[8] = {zz0.x, zz0.y, zz0.z, zz0.w, zz1.x, zz1.y, zz1.z, zz1.w};
        float ir[8] = {it0.x, it0.y, it0.z, it0.w, it1.x, it1.y, it1.z, it1.w};

        float diff[8];
        float ss = 0.f;
        #pragma unroll
        for (int d = 0; d < 8; ++d) {
            float df = xb[d] * ir[d] - zr[d];   // x/T - z
            diff[d] = df * ir[d];               // pre-scale by 1/T for dd
            ss = fmaf(df, df, ss);
        }
        float dist = __builtin_amdgcn_sqrtf(ss);
        // exp(-dist), dist in [0, ~25]: no overflow/underflow; max-sub skipped.
        e[k] = __builtin_amdgcn_exp2f(-dist * LOG2E);
        float inv = __builtin_amdgcn_rcpf(dist + 1e-6f);
        #pragma unroll
        for (int d = 0; d < 8; ++d) dd[k][d] = diff[d] * inv;
    }

    // ---- 9 independent wave reductions: se = sum e, acc[d] = sum e*dd ----
    float se = e[0] + e[1] + e[2] + e[3] + e[4] + e[5] + e[6] + e[7];
    float acc[8];
    #pragma unroll
    for (int d = 0; d < 8; ++d) {
        float a = 0.f;
        #pragma unroll
        for (int k = 0; k < 8; ++k) a = fmaf(e[k], dd[k][d], a);
        acc[d] = a;
    }
    #pragma unroll
    for (int o = 32; o > 0; o >>= 1) {
        se += __shfl_xor(se, o, 64);
        #pragma unroll
        for (int d = 0; d < 8; ++d) acc[d] += __shfl_xor(acc[d], o, 64);
    }
    const float sinv = __builtin_amdgcn_rcpf(se);

    // ---- W stores first (start HBM early) ----
    float w[8];
    float* outW = out + (size_t)b * M_N;
    #pragma unroll
    for (int k = 0; k < 8; ++k) {
        w[k] = e[k] * sinv;
        __builtin_nontemporal_store(w[k], outW + k * 64 + lane);
    }

    // ---- deriv = w*(mean - dd), mean[d] = acc[d]*sinv ----
    float meanv[8];
    #pragma unroll
    for (int d = 0; d < 8; ++d) meanv[d] = acc[d] * sinv;

    float* outD = out + (size_t)B_N * M_N + (size_t)b * (D_N * M_N);
    #pragma unroll
    for (int d = 0; d < 8; ++d) {
        #pragma unroll
        for (int k = 0; k < 8; ++k) {
            float v = w[k] * (meanv[d] - dd[k][d]);
            __builtin_nontemporal_store(v, outD + d * M_N + k * 64 + lane);
        }
    }
}

extern "C" void kernel_launch(void* const* d_in, const int* in_sizes, int n_in,
                              void* d_out, int out_size, void* d_ws, size_t ws_size,
                              hipStream_t stream) {
    const float* x = (const float*)d_in[0];
    const float* z = (const float*)d_in[1];
    const float* T = (const float*)d_in[2];
    float* out = (float*)d_out;

    dim3 grid(B_N / 8);   // 8 waves per block, 1 batch row per wave
    dim3 block(512);
    dsoftki_kernel<<<grid, block, 0, stream>>>(x, z, T, out);
}